// Round 6
// baseline (65.572 us; speedup 1.0000x reference)
//
#include <hip/hip_runtime.h>

// G=16, H=8, N=128/side, HD=32, D=256
// Head h of graph g = GEMM-output rows g*128+h*16 .. +16, ALL 256 cols,
// viewed flat as [128 nodes][32]; node ni = flat (ni*32+ki) within that 16x256 chunk.
#define C2L2E 2.8853900817779268f   // 2*log2(e)
#define LOG2E 1.4426950408889634f

// ws float offsets
#define WS_X1  0          // [gh][128*32] node-major (== 16x256 row-major chunk)
#define WS_X2  524288     // [gh][128*32]
#define WS_RS  1048576    // [gh][128] row sums
#define WS_CP  1064960    // [gh][2][128] col partials (per i-half)

// LDS float offsets (W tile aliases the att SMAT region; barrier-separated)
#define L_W    0          // 256*32 = 8192 (swizzled W k-tile)
#define L_SMAT 0          // 64*132 = 8448
#define L_COLP 8448       // 4*128
#define L_RED8 8960       // 64*4
#define L_X2   9216       // 128*32 (swizzled)
#define L_X1   13312      // 64*32 (swizzled)
// total 15360 floats = 60 KiB

__device__ __forceinline__ int swz4(int row, int c4) { return (c4 ^ (row & 7)) << 2; }

// ================= Kernel A: per-(gh,half) GEMM chunks + tanh-att partials =================
// grid 256: block = (gh, s). 512 threads: c = tid&255 (output column), rh = tid>>8.
__global__ __launch_bounds__(512) void ka_gemm_att(
        const float* __restrict__ A, const float* __restrict__ B,
        const float* __restrict__ W1, const float* __restrict__ b1,
        const float* __restrict__ W2, const float* __restrict__ b2,
        const float* __restrict__ q, float* __restrict__ ws) {
    __shared__ float sm[15360];
    const int tid = threadIdx.x;
    const int gh = blockIdx.x >> 1, s = blockIdx.x & 1;
    const int g = gh >> 3, h = gh & 7;
    const int rowbase = g * 128 + h * 16;   // first GEMM row of this (g,h) chunk
    float* x2L = sm + L_X2;
    float* x1L = sm + L_X1;
    float* lw  = sm + L_W;

    const int c = tid & 255;                                   // per-lane: consecutive cols
    const int rh = __builtin_amdgcn_readfirstlane(tid >> 8);   // 0..1, wave-uniform
    const int csw = (c & 7);                                   // read-swizzle key

    // ---- Phase A: x2 chunk rows 0..15; this thread: rows rh*8..+8, col c. W2 via LDS k-tiles.
    {
        float acc[8];
        #pragma unroll
        for (int r = 0; r < 8; ++r) acc[r] = 0.f;
        for (int kt = 0; kt < 8; ++kt) {
            __syncthreads();
            #pragma unroll
            for (int p = 0; p < 4; ++p) {              // stage 32KB tile, coalesced
                int n = tid + p * 512;                 // float4 id
                int cw = n >> 3, k4 = n & 7;
                float4 v = *(const float4*)(W2 + (size_t)cw * 256 + kt * 32 + k4 * 4);
                *(float4*)(lw + cw * 32 + ((k4 ^ (cw & 7)) << 2)) = v;
            }
            __syncthreads();
            const float* brow = B + (size_t)(rowbase + rh * 8) * 256 + kt * 32;
            #pragma unroll
            for (int k4 = 0; k4 < 8; ++k4) {
                float4 wv = *(const float4*)(lw + c * 32 + ((k4 ^ csw) << 2));
                #pragma unroll
                for (int r = 0; r < 8; ++r) {
                    float4 av = *(const float4*)(brow + r * 256 + k4 * 4);  // wave-uniform
                    acc[r] = fmaf(wv.x, av.x, acc[r]);
                    acc[r] = fmaf(wv.y, av.y, acc[r]);
                    acc[r] = fmaf(wv.z, av.z, acc[r]);
                    acc[r] = fmaf(wv.w, av.w, acc[r]);
                }
            }
        }
        const float bb = b2[c];
        #pragma unroll
        for (int r = 0; r < 8; ++r) {
            float v = acc[r] + bb;
            int f = (rh * 8 + r) * 256 + c;        // flat node-major idx in chunk
            int ni = f >> 5, ki = f & 31;
            x2L[ni * 32 + swz4(ni, ki >> 2) + (ki & 3)] = v;
            if (rh == s)
                ws[WS_X2 + (size_t)gh * 4096 + f] = v;
        }
    }

    // ---- Phase B: x1 own half = chunk rows s*8..+8; this thread: rows s*8+rh*4..+4, col c
    {
        float acc[4];
        #pragma unroll
        for (int r = 0; r < 4; ++r) acc[r] = 0.f;
        for (int kt = 0; kt < 8; ++kt) {
            __syncthreads();                       // protect prior tile reads (incl. phase A)
            #pragma unroll
            for (int p = 0; p < 4; ++p) {
                int n = tid + p * 512;
                int cw = n >> 3, k4 = n & 7;
                float4 v = *(const float4*)(W1 + (size_t)cw * 256 + kt * 32 + k4 * 4);
                *(float4*)(lw + cw * 32 + ((k4 ^ (cw & 7)) << 2)) = v;
            }
            __syncthreads();
            const float* arow = A + (size_t)(rowbase + s * 8 + rh * 4) * 256 + kt * 32;
            #pragma unroll
            for (int k4 = 0; k4 < 8; ++k4) {
                float4 wv = *(const float4*)(lw + c * 32 + ((k4 ^ csw) << 2));
                #pragma unroll
                for (int r = 0; r < 4; ++r) {
                    float4 av = *(const float4*)(arow + r * 256 + k4 * 4);  // wave-uniform
                    acc[r] = fmaf(wv.x, av.x, acc[r]);
                    acc[r] = fmaf(wv.y, av.y, acc[r]);
                    acc[r] = fmaf(wv.z, av.z, acc[r]);
                    acc[r] = fmaf(wv.w, av.w, acc[r]);
                }
            }
        }
        const float bb = b1[c];
        #pragma unroll
        for (int r = 0; r < 4; ++r) {
            float v = acc[r] + bb;
            int f = (rh * 4 + r) * 256 + c;        // local flat 0..2047 (64 local nodes)
            int nl = f >> 5, ki = f & 31;
            x1L[nl * 32 + swz4(nl, ki >> 2) + (ki & 3)] = v;
            ws[WS_X1 + (size_t)gh * 4096 + s * 2048 + f] = v;
        }
    }
    __syncthreads();

    // ---- att: S(i,j) = sum_k (-2 q_k)/(exp2(2log2e*x1*x2)+1); uniform Qsum shift dropped
    {
        const int j = tid & 127, iset = tid >> 7;
        float xr[32], qt[32];
        #pragma unroll
        for (int cc = 0; cc < 8; ++cc) {
            float4 v = *(float4*)(x2L + j * 32 + swz4(j, cc));
            xr[cc*4+0] = v.x * C2L2E; xr[cc*4+1] = v.y * C2L2E;
            xr[cc*4+2] = v.z * C2L2E; xr[cc*4+3] = v.w * C2L2E;
            float4 qv = *(const float4*)(q + cc * 4);
            qt[cc*4+0] = -2.f * qv.x; qt[cc*4+1] = -2.f * qv.y;
            qt[cc*4+2] = -2.f * qv.z; qt[cc*4+3] = -2.f * qv.w;
        }
        float colacc = 0.f;
        for (int rr = 0; rr < 16; ++rr) {
            const int r = iset * 16 + rr;          // local i (global i = s*64 + r)
            float a[32];
            #pragma unroll
            for (int cc = 0; cc < 8; ++cc) {
                float4 v = *(float4*)(x1L + r * 32 + swz4(r, cc));
                a[cc*4+0] = v.x; a[cc*4+1] = v.y; a[cc*4+2] = v.z; a[cc*4+3] = v.w;
            }
            float S0 = 0.f, S1 = 0.f;
            #pragma unroll
            for (int kp = 0; kp < 16; ++kp) {
                float p0 = a[2*kp]   * xr[2*kp];
                float p1 = a[2*kp+1] * xr[2*kp+1];
                float d0 = __builtin_amdgcn_exp2f(fminf(p0, 60.f)) + 1.f;
                float d1 = __builtin_amdgcn_exp2f(fminf(p1, 60.f)) + 1.f;
                float rD = __builtin_amdgcn_rcpf(d0 * d1);
                float U  = fmaf(qt[2*kp+1], d0, qt[2*kp] * d1);
                if (kp & 1) S1 = fmaf(U, rD, S1); else S0 = fmaf(U, rD, S0);
            }
            float S = S0 + S1;
            colacc += S;
            sm[L_SMAT + r * 132 + j] = S;
        }
        sm[L_COLP + iset * 128 + j] = colacc;
    }
    __syncthreads();

    // ---- partial reductions -> ws
    if (tid < 256) {
        const int row = tid >> 2, seg = tid & 3;
        float acc = 0.f;
        #pragma unroll
        for (int m = 0; m < 8; ++m) {
            float4 v = *(float4*)(sm + L_SMAT + row * 132 + seg * 32 + m * 4);
            acc += (v.x + v.y) + (v.z + v.w);
        }
        sm[L_RED8 + row * 4 + seg] = acc;
    }
    __syncthreads();
    if (tid < 64) {
        float v = sm[L_RED8 + tid*4] + sm[L_RED8 + tid*4+1]
                + sm[L_RED8 + tid*4+2] + sm[L_RED8 + tid*4+3];
        ws[WS_RS + gh * 128 + s * 64 + tid] = v;
    } else if (tid < 192) {
        const int j = tid - 64;
        ws[WS_CP + (size_t)(gh * 2 + s) * 128 + j] =
            sm[L_COLP + j] + sm[L_COLP + 128 + j] + sm[L_COLP + 256 + j] + sm[L_COLP + 384 + j];
    }
}

// ================= Kernel B: softmaxes + weighted sums -> out =================
// grid 128 (one per gh), 256 threads: side=tid>>7 (0:A,1:B), u=tid&127
__global__ __launch_bounds__(256) void kb_finish(
        const float* __restrict__ ws, float* __restrict__ out) {
    const int gh = blockIdx.x;
    const int g = gh >> 3, h = gh & 7;
    const int tid = threadIdx.x;
    const int side = tid >> 7;
    const int u = tid & 127;
    const int w2 = (u >> 6) & 1;
    const int lane = tid & 63;

    __shared__ float warr[2][128];
    __shared__ float red[4];
    __shared__ float red2[4];
    __shared__ float part[2][4][32];

    float m;
    if (side == 0) {
        m = ws[WS_RS + gh * 128 + u] * 0.0078125f;                     // mean over j
    } else {
        m = (ws[WS_CP + (size_t)(gh * 2 + 0) * 128 + u] +
             ws[WS_CP + (size_t)(gh * 2 + 1) * 128 + u]) * 0.0078125f; // mean over i
    }

    float mx = m;
    #pragma unroll
    for (int d = 32; d >= 1; d >>= 1) mx = fmaxf(mx, __shfl_xor(mx, d));
    if (lane == 0) red[side * 2 + w2] = mx;
    __syncthreads();
    mx = fmaxf(red[side * 2], red[side * 2 + 1]);

    float e = __builtin_amdgcn_exp2f((m - mx) * LOG2E);
    float sme = e;
    #pragma unroll
    for (int d = 32; d >= 1; d >>= 1) sme += __shfl_xor(sme, d);
    if (lane == 0) red2[side * 2 + w2] = sme;
    __syncthreads();
    const float tot = red2[side * 2] + red2[side * 2 + 1];
    warr[side][u] = e * __builtin_amdgcn_rcpf(tot);
    __syncthreads();

    const int k = u & 31, is = u >> 5;
    const float* xt = ws + (side ? WS_X2 : WS_X1) + (size_t)gh * 4096;
    float p = 0.f;
    #pragma unroll 4
    for (int r = 0; r < 32; ++r)
        p = fmaf(xt[(is * 32 + r) * 32 + k], warr[side][is * 32 + r], p);
    part[side][is][k] = p;
    __syncthreads();
    if (u < 32 && side == 0) {
        float o = part[0][0][u] + part[0][1][u] + part[0][2][u] + part[0][3][u];
        out[(size_t)g * 512 + h * 32 + u] = o;
    } else if (u < 32 && side == 1) {
        float o = part[1][0][u] + part[1][1][u] + part[1][2][u] + part[1][3][u];
        out[(size_t)g * 512 + 256 + h * 32 + u] = o;
    }
}

extern "C" void kernel_launch(void* const* d_in, const int* in_sizes, int n_in,
                              void* d_out, int out_size, void* d_ws, size_t ws_size,
                              hipStream_t stream) {
    const float* A  = (const float*)d_in[0];
    const float* B  = (const float*)d_in[2];
    const float* W1 = (const float*)d_in[4];
    const float* b1 = (const float*)d_in[5];
    const float* W2 = (const float*)d_in[6];
    const float* b2 = (const float*)d_in[7];
    const float* q  = (const float*)d_in[8];
    float* ws  = (float*)d_ws;
    float* out = (float*)d_out;

    ka_gemm_att<<<256, 512, 0, stream>>>(A, B, W1, b1, W2, b2, q, ws);
    kb_finish<<<128, 256, 0, stream>>>(ws, out);
}

// Round 7
// 41.809 us; speedup vs baseline: 1.5684x; 1.5684x over previous
//
#include <hip/hip_runtime.h>

// G=16, H=8, N=128/side, HD=32, D=256
// Head chunk layout fact: ws x tensors are plain row-major [2048][256];
// head (g,h) chunk = rows g*128+h*16..+16 viewed flat as [128 nodes][32].
#define C2L2E 2.8853900817779268f   // 2*log2(e)
#define LOG2E 1.4426950408889634f

// ws float offsets
#define WS_X1  0          // [2048][256] row-major x1
#define WS_X2  524288     // [2048][256] row-major x2
#define WS_RS  1048576    // [gh][128] row sums
#define WS_CP  1064960    // [gh][2][128] col partials (per i-half)

// K2 LDS float offsets
#define L_SMAT 0          // 64*132 = 8448
#define L_COLP 8448       // 4*128
#define L_RED8 8960       // 64*4
#define L_X2   9216       // 128*32 swizzled
#define L_X1   13312      // 64*32 swizzled
// total 15360 floats = 60 KiB

__device__ __forceinline__ int swz4(int row, int c4) { return (c4 ^ (row & 7)) << 2; }

// ================= K1: tiled GEMM x = In @ W^T + bias =================
// grid 512: idx=bid&255 -> mt=idx>>2 (32-row tile), nt=idx&3 (64-col tile); mat=bid>>8.
// 256 threads: tm=tid&7 (4 rows), tn=tid>>3 (2 cols). BK=32, double-buffered LDS.
__global__ __launch_bounds__(256) void k1_gemm(
        const float* __restrict__ A, const float* __restrict__ B,
        const float* __restrict__ W1, const float* __restrict__ b1,
        const float* __restrict__ W2, const float* __restrict__ b2,
        float* __restrict__ ws) {
    __shared__ float At[2][32 * 36];   // [k][m], pad 36
    __shared__ float Wt[2][32 * 68];   // [k][n], pad 68
    const int tid = threadIdx.x, bid = blockIdx.x;
    const int idx = bid & 255, mat = bid >> 8;
    const int r0 = (idx >> 2) * 32, c0 = (idx & 3) * 64;
    const float* In = mat ? B : A;
    const float* W  = mat ? W2 : W1;
    const float* bs = mat ? b2 : b1;
    float* xo = ws + (mat ? WS_X2 : WS_X1);

    const int tm = tid & 7, tn = tid >> 3;
    const int arow = tid >> 3, akq = tid & 7;   // stage mapping (n = tid)

    float acc[4][2];
    #pragma unroll
    for (int i = 0; i < 4; ++i) { acc[i][0] = 0.f; acc[i][1] = 0.f; }

    // prologue: stage kt=0 into buffer 0
    {
        float4 av = *(const float4*)(In + (size_t)(r0 + arow) * 256 + akq * 4);
        At[0][(akq*4+0)*36 + arow] = av.x;
        At[0][(akq*4+1)*36 + arow] = av.y;
        At[0][(akq*4+2)*36 + arow] = av.z;
        At[0][(akq*4+3)*36 + arow] = av.w;
        float4 w0 = *(const float4*)(W + (size_t)(c0 + arow) * 256 + akq * 4);
        Wt[0][(akq*4+0)*68 + arow] = w0.x;
        Wt[0][(akq*4+1)*68 + arow] = w0.y;
        Wt[0][(akq*4+2)*68 + arow] = w0.z;
        Wt[0][(akq*4+3)*68 + arow] = w0.w;
        float4 w1v = *(const float4*)(W + (size_t)(c0 + 32 + arow) * 256 + akq * 4);
        Wt[0][(akq*4+0)*68 + 32 + arow] = w1v.x;
        Wt[0][(akq*4+1)*68 + 32 + arow] = w1v.y;
        Wt[0][(akq*4+2)*68 + 32 + arow] = w1v.z;
        Wt[0][(akq*4+3)*68 + 32 + arow] = w1v.w;
    }
    __syncthreads();

    for (int kt = 0; kt < 8; ++kt) {
        const int b = kt & 1;
        float4 av, w0, w1v;
        if (kt < 7) {   // issue next-tile loads before compute
            av  = *(const float4*)(In + (size_t)(r0 + arow) * 256 + (kt+1)*32 + akq * 4);
            w0  = *(const float4*)(W + (size_t)(c0 + arow) * 256 + (kt+1)*32 + akq * 4);
            w1v = *(const float4*)(W + (size_t)(c0 + 32 + arow) * 256 + (kt+1)*32 + akq * 4);
        }
        #pragma unroll
        for (int k = 0; k < 32; ++k) {
            float4 a4 = *(const float4*)(&At[b][k*36 + tm*4]);
            float2 w2 = *(const float2*)(&Wt[b][k*68 + tn*2]);
            acc[0][0] = fmaf(a4.x, w2.x, acc[0][0]);
            acc[0][1] = fmaf(a4.x, w2.y, acc[0][1]);
            acc[1][0] = fmaf(a4.y, w2.x, acc[1][0]);
            acc[1][1] = fmaf(a4.y, w2.y, acc[1][1]);
            acc[2][0] = fmaf(a4.z, w2.x, acc[2][0]);
            acc[2][1] = fmaf(a4.z, w2.y, acc[2][1]);
            acc[3][0] = fmaf(a4.w, w2.x, acc[3][0]);
            acc[3][1] = fmaf(a4.w, w2.y, acc[3][1]);
        }
        if (kt < 7) {
            const int nb = b ^ 1;
            At[nb][(akq*4+0)*36 + arow] = av.x;
            At[nb][(akq*4+1)*36 + arow] = av.y;
            At[nb][(akq*4+2)*36 + arow] = av.z;
            At[nb][(akq*4+3)*36 + arow] = av.w;
            Wt[nb][(akq*4+0)*68 + arow] = w0.x;
            Wt[nb][(akq*4+1)*68 + arow] = w0.y;
            Wt[nb][(akq*4+2)*68 + arow] = w0.z;
            Wt[nb][(akq*4+3)*68 + arow] = w0.w;
            Wt[nb][(akq*4+0)*68 + 32 + arow] = w1v.x;
            Wt[nb][(akq*4+1)*68 + 32 + arow] = w1v.y;
            Wt[nb][(akq*4+2)*68 + 32 + arow] = w1v.z;
            Wt[nb][(akq*4+3)*68 + 32 + arow] = w1v.w;
            __syncthreads();
        }
    }

    const float2 bv = *(const float2*)(bs + c0 + tn * 2);
    #pragma unroll
    for (int i = 0; i < 4; ++i) {
        float2 o; o.x = acc[i][0] + bv.x; o.y = acc[i][1] + bv.y;
        *(float2*)(xo + (size_t)(r0 + tm*4 + i) * 256 + c0 + tn * 2) = o;
    }
}

// ================= K2: tanh-att partials =================
// grid 256: block = (gh, s). 512 threads. Stages x tiles from ws, att core verbatim (verified).
__global__ __launch_bounds__(512) void k2_att(
        float* __restrict__ ws, const float* __restrict__ q) {
    __shared__ float sm[15360];
    const int tid = threadIdx.x;
    const int gh = blockIdx.x >> 1, s = blockIdx.x & 1;
    float* x2L = sm + L_X2;
    float* x1L = sm + L_X1;

    // stage x2 full chunk (128x32) + x1 own half (64x32), swizzled
    {
        const float4* src2 = (const float4*)(ws + WS_X2 + (size_t)gh * 4096);
        #pragma unroll
        for (int p = 0; p < 2; ++p) {
            int n = tid + p * 512;              // float4 idx 0..1023
            float4 v = src2[n];
            int ni = n >> 3, c4 = n & 7;
            *(float4*)(x2L + ni * 32 + swz4(ni, c4)) = v;
        }
        const float4* src1 = (const float4*)(ws + WS_X1 + (size_t)gh * 4096 + s * 2048);
        float4 v = src1[tid];                   // float4 idx 0..511
        int nl = tid >> 3, c4 = tid & 7;
        *(float4*)(x1L + nl * 32 + swz4(nl, c4)) = v;
    }
    __syncthreads();

    // att: S(i,j) = sum_k (-2 q_k)/(exp2(2log2e*x1*x2)+1); uniform Qsum shift dropped
    {
        const int j = tid & 127, iset = tid >> 7;
        float xr[32], qt[32];
        #pragma unroll
        for (int cc = 0; cc < 8; ++cc) {
            float4 v = *(float4*)(x2L + j * 32 + swz4(j, cc));
            xr[cc*4+0] = v.x * C2L2E; xr[cc*4+1] = v.y * C2L2E;
            xr[cc*4+2] = v.z * C2L2E; xr[cc*4+3] = v.w * C2L2E;
            float4 qv = *(const float4*)(q + cc * 4);
            qt[cc*4+0] = -2.f * qv.x; qt[cc*4+1] = -2.f * qv.y;
            qt[cc*4+2] = -2.f * qv.z; qt[cc*4+3] = -2.f * qv.w;
        }
        float colacc = 0.f;
        for (int rr = 0; rr < 16; ++rr) {
            const int r = iset * 16 + rr;       // local i (global i = s*64 + r)
            float a[32];
            #pragma unroll
            for (int cc = 0; cc < 8; ++cc) {
                float4 v = *(float4*)(x1L + r * 32 + swz4(r, cc));
                a[cc*4+0] = v.x; a[cc*4+1] = v.y; a[cc*4+2] = v.z; a[cc*4+3] = v.w;
            }
            float S0 = 0.f, S1 = 0.f;
            #pragma unroll
            for (int kp = 0; kp < 16; ++kp) {
                float p0 = a[2*kp]   * xr[2*kp];
                float p1 = a[2*kp+1] * xr[2*kp+1];
                float d0 = __builtin_amdgcn_exp2f(fminf(p0, 60.f)) + 1.f;
                float d1 = __builtin_amdgcn_exp2f(fminf(p1, 60.f)) + 1.f;
                float rD = __builtin_amdgcn_rcpf(d0 * d1);
                float U  = fmaf(qt[2*kp+1], d0, qt[2*kp] * d1);
                if (kp & 1) S1 = fmaf(U, rD, S1); else S0 = fmaf(U, rD, S0);
            }
            float S = S0 + S1;
            colacc += S;
            sm[L_SMAT + r * 132 + j] = S;
        }
        sm[L_COLP + iset * 128 + j] = colacc;
    }
    __syncthreads();

    // partial reductions -> ws
    if (tid < 256) {
        const int row = tid >> 2, seg = tid & 3;
        float acc = 0.f;
        #pragma unroll
        for (int m = 0; m < 8; ++m) {
            float4 v = *(float4*)(sm + L_SMAT + row * 132 + seg * 32 + m * 4);
            acc += (v.x + v.y) + (v.z + v.w);
        }
        sm[L_RED8 + row * 4 + seg] = acc;
    }
    __syncthreads();
    if (tid < 64) {
        float v = sm[L_RED8 + tid*4] + sm[L_RED8 + tid*4+1]
                + sm[L_RED8 + tid*4+2] + sm[L_RED8 + tid*4+3];
        ws[WS_RS + gh * 128 + s * 64 + tid] = v;
    } else if (tid < 192) {
        const int j = tid - 64;
        ws[WS_CP + (size_t)(gh * 2 + s) * 128 + j] =
            sm[L_COLP + j] + sm[L_COLP + 128 + j] + sm[L_COLP + 256 + j] + sm[L_COLP + 384 + j];
    }
}

// ================= K3: softmaxes + weighted sums -> out =================
// grid 128 (one per gh), 256 threads: side=tid>>7 (0:A,1:B), u=tid&127
__global__ __launch_bounds__(256) void kb_finish(
        const float* __restrict__ ws, float* __restrict__ out) {
    const int gh = blockIdx.x;
    const int g = gh >> 3, h = gh & 7;
    const int tid = threadIdx.x;
    const int side = tid >> 7;
    const int u = tid & 127;
    const int w2 = (u >> 6) & 1;
    const int lane = tid & 63;

    __shared__ float warr[2][128];
    __shared__ float red[4];
    __shared__ float red2[4];
    __shared__ float part[2][4][32];

    float m;
    if (side == 0) {
        m = ws[WS_RS + gh * 128 + u] * 0.0078125f;                     // mean over j
    } else {
        m = (ws[WS_CP + (size_t)(gh * 2 + 0) * 128 + u] +
             ws[WS_CP + (size_t)(gh * 2 + 1) * 128 + u]) * 0.0078125f; // mean over i
    }

    float mx = m;
    #pragma unroll
    for (int d = 32; d >= 1; d >>= 1) mx = fmaxf(mx, __shfl_xor(mx, d));
    if (lane == 0) red[side * 2 + w2] = mx;
    __syncthreads();
    mx = fmaxf(red[side * 2], red[side * 2 + 1]);

    float e = __builtin_amdgcn_exp2f((m - mx) * LOG2E);
    float sme = e;
    #pragma unroll
    for (int d = 32; d >= 1; d >>= 1) sme += __shfl_xor(sme, d);
    if (lane == 0) red2[side * 2 + w2] = sme;
    __syncthreads();
    const float tot = red2[side * 2] + red2[side * 2 + 1];
    warr[side][u] = e * __builtin_amdgcn_rcpf(tot);
    __syncthreads();

    const int k = u & 31, is = u >> 5;
    const float* xt = ws + (side ? WS_X2 : WS_X1) + (size_t)gh * 4096;
    float p = 0.f;
    #pragma unroll 4
    for (int r = 0; r < 32; ++r)
        p = fmaf(xt[(is * 32 + r) * 32 + k], warr[side][is * 32 + r], p);
    part[side][is][k] = p;
    __syncthreads();
    if (u < 32 && side == 0) {
        float o = part[0][0][u] + part[0][1][u] + part[0][2][u] + part[0][3][u];
        out[(size_t)g * 512 + h * 32 + u] = o;
    } else if (u < 32 && side == 1) {
        float o = part[1][0][u] + part[1][1][u] + part[1][2][u] + part[1][3][u];
        out[(size_t)g * 512 + 256 + h * 32 + u] = o;
    }
}

extern "C" void kernel_launch(void* const* d_in, const int* in_sizes, int n_in,
                              void* d_out, int out_size, void* d_ws, size_t ws_size,
                              hipStream_t stream) {
    const float* A  = (const float*)d_in[0];
    const float* B  = (const float*)d_in[2];
    const float* W1 = (const float*)d_in[4];
    const float* b1 = (const float*)d_in[5];
    const float* W2 = (const float*)d_in[6];
    const float* b2 = (const float*)d_in[7];
    const float* q  = (const float*)d_in[8];
    float* ws  = (float*)d_ws;
    float* out = (float*)d_out;

    k1_gemm<<<512, 256, 0, stream>>>(A, B, W1, b1, W2, b2, ws);
    k2_att<<<256, 512, 0, stream>>>(ws, q);
    kb_finish<<<128, 256, 0, stream>>>(ws, out);
}